// Round 9
// baseline (110.267 us; speedup 1.0000x reference)
//
#include <hip/hip_runtime.h>
#include <hip/hip_bf16.h>

#define N_PIX 8192
#define C_DIM 128
#define HW 4096
// exp(dot/0.1) = exp2(dot * 14.42695...); fold sqrt of that into each vector.
#define PRESCALE 3.7982825f  // sqrt(log2(e)/0.1)
#define NUM_CLASSES 4
#define TOTAL_BLOCKS (64 * 33)

typedef __attribute__((ext_vector_type(8))) short short8;   // 8 x bf16 (4 VGPRs)
typedef __attribute__((ext_vector_type(4))) float float4v;  // 4 x f32 acc

// Fragment-linear layout (R7 win): ebfT[((T*4 + s)*64 + lane)*8 + j] = e[T*16 + lq][s*32 + quad*8 + j],
// lane = quad*16 + lq. Fragment load = base + lane*16B: one coalesced 1KB dwordx4.

// ---------------- Kernel 1: L2-normalize + prescale + bf16 cast into ebfT; zero pos/tot/cnt ----------------
__global__ __launch_bounds__(256) void normscale_kernel(const float* __restrict__ emb,
                                                        unsigned short* __restrict__ ebfT,
                                                        float* __restrict__ pz,
                                                        unsigned* __restrict__ cnt) {
    const int tid = threadIdx.x;
    const int p16 = tid & 15;   // pixel within tile (lq)
    const int g = tid >> 4;     // channel group 0..15 (8 channels each)
    const int n = blockIdx.x * 16 + p16;
    const int b = n >> 12;
    const int hw = n & (HW - 1);
    const float* base = emb + b * (C_DIM * HW) + hw;

    float v[8];
    float ss = 0.f;
#pragma unroll
    for (int i = 0; i < 8; ++i) {
        v[i] = base[(g * 8 + i) * HW];
        ss += v[i] * v[i];
    }
    ss += __shfl_xor(ss, 16, 64);
    ss += __shfl_xor(ss, 32, 64);
    __shared__ float red[4][16];
    const int wv = tid >> 6;
    if ((tid & 63) < 16) red[wv][p16] = ss;
    __syncthreads();
    float tot = red[0][p16] + red[1][p16] + red[2][p16] + red[3][p16];
    float inv = PRESCALE / fmaxf(sqrtf(tot), 1e-12f);

    unsigned short us[8];
#pragma unroll
    for (int i = 0; i < 8; ++i) {
        __hip_bfloat16 h = __float2bfloat16(v[i] * inv);
        us[i] = *reinterpret_cast<unsigned short*>(&h);
    }
    const int s = g >> 2, quad = g & 3;
    unsigned short* dst = ebfT + (((blockIdx.x * 4 + s) * 64 + quad * 16 + p16) << 3);
    *reinterpret_cast<short8*>(dst) = *reinterpret_cast<short8*>(us);

    if (blockIdx.x < 64) pz[blockIdx.x * 256 + tid] = 0.f;   // zeroes pos[8192]+tot[8192]
    if (blockIdx.x == 64 && tid == 0) cnt[0] = 0u;
}

// ---------------- Kernel 2: symmetric fused S = e e^T, exp2, row+col sums, fused finalize ----------------
// Grid (64, 33): bi = I-panel (128 rows).
//   d = blockIdx.y+1 in 1..32: off-diag pair blocks, jp=(bi+d)%64 (d=32 double-covers ->
//   bi>=32 blocks skip work, but still hit the completion counter). d==33: diagonal blocks (R20).
// R22 (this round): finalize fused into the LAST pairwise block. R15's version of this died
//   on __threadfence = per-block L2 writeback+INVALIDATE (wiped ebfT for in-flight blocks).
//   Safe recipe: __syncthreads() (compiler drains each wave's vmcnt before s_barrier -> all
//   this block's device-scope atomics are complete AT the coherence point), then tid0 does
//   fetch_add with __ATOMIC_RELEASE (waitcnt + cheap writeback of the ~zero dirty L2 lines;
//   NO invalidate). Last block reads pos/tot with agent-scope RELAXED atomic loads (straight
//   from the coherence point; proven correct in R15b/R21). All blocks are 8 tiles (R20 diag
//   split), so the ~3us finalize tail on one block replaces the separate kernel + launch gap.
//   TRIPWIRE: if RELEASE lowers to an invalidate, pairwise will exceed the 41.7us fills and
//   show in top-5 -> revert.
// R21 FAILED (94.6): atomic-free tail (unique-slot stores + reduce kernel) = +7us. The
//   end-of-kernel atomic burst is CHEAP (<=2us); extra launch + coherence-point reduce cost
//   more. Atomics exonerated (2nd confirmation of R13). REVERTED.
// R14: col-side partials -> LDS per tile, reduced once per block, one atomic per column.
// R16 NEUTRAL: manual B-pipeline (load latency already hidden). R20 NEUTRAL: diag split (kept
//   anyway - uniform 8-tile blocks are what makes R22's fusion safe).
// R17/R18 FAILED: __launch_bounds__ min-waves > 4 ALWAYS spills this kernel. (256,4) final.
// HARD-WON toolchain rules:
//   *** NEVER fully `#pragma unroll` the MFMA tile loop *** (hoists all B loads -> spill).
//   `#pragma unroll 2` is the sweet spot. R5: no global_load_lds. R6: no lambdas; reg arrays
//   statically indexed only. R15: NO __threadfence anywhere.
__global__ __launch_bounds__(256, 4) void pairwise_kernel(const unsigned short* __restrict__ ebfT,
                                                          const int* __restrict__ lab,
                                                          float* __restrict__ pos,
                                                          float* __restrict__ tot,
                                                          unsigned* __restrict__ cnt,
                                                          float* __restrict__ out) {
    const int bi = blockIdx.x;
    const int d = blockIdx.y + 1;          // 1..33
    const bool culled = (d == 32 && bi >= 32);  // wrap double-cover cull (block-uniform)
    const bool diag = (d == 33);                // dedicated diagonal blocks (block-uniform)

    const int wave = threadIdx.x >> 6;
    const int lane = threadIdx.x & 63;
    const int quad = lane >> 4;
    const int lq = lane & 15;

    // [wave][tile][lane] col-side partials (x=tot, y=pos). 16 KiB.
    __shared__ float2 cpart[4][8][64];
    __shared__ unsigned slast;

    if (!culled) {
        const int jp = diag ? bi : ((bi + d) & 63);
        const int Ipanel = bi << 7;
        const int Jpanel = jp << 7;
        const int I0 = Ipanel + wave * 32;

        // A fragments: tiles (I0>>4), (I0>>4)+1 — coalesced lane*16B loads.
        short8 afrag[2][4];
#pragma unroll
        for (int a = 0; a < 2; ++a) {
            const unsigned short* ab = ebfT + ((((I0 >> 4) + a) * 4) * 64 + lane) * 8;
#pragma unroll
            for (int s = 0; s < 4; ++s)
                afrag[a][s] = *reinterpret_cast<const short8*>(ab + s * 512);
        }
        int lab_row[2][4];
#pragma unroll
        for (int a = 0; a < 2; ++a)
#pragma unroll
            for (int r = 0; r < 4; ++r) lab_row[a][r] = lab[I0 + a * 16 + quad * 4 + r];

        float tacc[2][4] = {};
        float pacc[2][4] = {};

        if (!diag) {
            // ---- Off-diagonal panel pair (no masking, row + col side) ----
            const unsigned short* bbase = ebfT + ((Jpanel >> 4) * 4 * 64 + lane) * 8;
#pragma unroll 2
            for (int t = 0; t < 8; ++t) {
                const int lab_col = lab[Jpanel + t * 16 + lq];
                const unsigned short* bt = bbase + t * 2048;
                short8 bfrag[4];
#pragma unroll
                for (int s = 0; s < 4; ++s)
                    bfrag[s] = *reinterpret_cast<const short8*>(bt + s * 512);

                float4v acc0 = {0.f, 0.f, 0.f, 0.f};
                float4v acc1 = {0.f, 0.f, 0.f, 0.f};
#pragma unroll
                for (int s = 0; s < 4; ++s) {
                    acc0 = __builtin_amdgcn_mfma_f32_16x16x32_bf16(afrag[0][s], bfrag[s], acc0, 0, 0, 0);
                    acc1 = __builtin_amdgcn_mfma_f32_16x16x32_bf16(afrag[1][s], bfrag[s], acc1, 0, 0, 0);
                }

                float colTs = 0.f, colPs = 0.f;
#pragma unroll
                for (int r = 0; r < 4; ++r) {
                    float ex = __builtin_amdgcn_exp2f(acc0[r]);
                    tacc[0][r] += ex;
                    float pxe = (lab_row[0][r] == lab_col) ? ex : 0.f;
                    pacc[0][r] += pxe;
                    colTs += ex;
                    colPs += pxe;
                }
#pragma unroll
                for (int r = 0; r < 4; ++r) {
                    float ex = __builtin_amdgcn_exp2f(acc1[r]);
                    tacc[1][r] += ex;
                    float pxe = (lab_row[1][r] == lab_col) ? ex : 0.f;
                    pacc[1][r] += pxe;
                    colTs += ex;
                    colPs += pxe;
                }
                // fire-and-forget ds_write_b64; reduction deferred to post-barrier gather.
                cpart[wave][t][lane] = make_float2(colTs, colPs);
            }
        } else {
            // ---- Diagonal panel (self-masked, row-side only; col sums == row sums by symmetry) ----
#define EPILOGUE(A, ACC, MASKED)                                            \
    {                                                                       \
        _Pragma("unroll") for (int r = 0; r < 4; ++r) {                     \
            float ex = __builtin_amdgcn_exp2f(ACC[r]);                      \
            if (MASKED) ex = (lq == quad * 4 + r) ? 0.f : ex;               \
            tacc[A][r] += ex;                                               \
            pacc[A][r] += (lab_row[A][r] == lab_col) ? ex : 0.f;            \
        }                                                                   \
    }
            const unsigned short* bbase = ebfT + ((Ipanel >> 4) * 4 * 64 + lane) * 8;
#pragma unroll 2
            for (int t = 0; t < 8; ++t) {
                const int J = Ipanel + t * 16;
                const int lab_col = lab[J + lq];
                const unsigned short* bt = bbase + t * 2048;
                short8 bfrag[4];
#pragma unroll
                for (int s = 0; s < 4; ++s)
                    bfrag[s] = *reinterpret_cast<const short8*>(bt + s * 512);

                float4v acc0 = {0.f, 0.f, 0.f, 0.f};
                float4v acc1 = {0.f, 0.f, 0.f, 0.f};
#pragma unroll
                for (int s = 0; s < 4; ++s) {
                    acc0 = __builtin_amdgcn_mfma_f32_16x16x32_bf16(afrag[0][s], bfrag[s], acc0, 0, 0, 0);
                    acc1 = __builtin_amdgcn_mfma_f32_16x16x32_bf16(afrag[1][s], bfrag[s], acc1, 0, 0, 0);
                }
                if (J == I0) EPILOGUE(0, acc0, true) else EPILOGUE(0, acc0, false);
                if (J == I0 + 16) EPILOGUE(1, acc1, true) else EPILOGUE(1, acc1, false);
            }
#undef EPILOGUE
        }

        // ---- Row-side flush: one atomic per row per block (before any barrier) ----
#pragma unroll
        for (int a = 0; a < 2; ++a) {
#pragma unroll
            for (int r = 0; r < 4; ++r) {
                float t = tacc[a][r], p = pacc[a][r];
#pragma unroll
                for (int off = 1; off < 16; off <<= 1) {
                    t += __shfl_xor(t, off, 64);
                    p += __shfl_xor(p, off, 64);
                }
                if (lq == 0) {
                    const int row = I0 + a * 16 + quad * 4 + r;
                    atomicAdd(&tot[row], t);
                    atomicAdd(&pos[row], p);
                }
            }
        }

        // ---- Col-side gather (off-diag only): one atomic per column ----
        if (!diag) {
            __syncthreads();
            if (threadIdx.x < 128) {
                const int j = threadIdx.x;          // column within J panel
                const int tt = j >> 4, jl = j & 15; // tile, lane-within-tile
                float st = 0.f, sp = 0.f;
#pragma unroll
                for (int w = 0; w < 4; ++w)
#pragma unroll
                    for (int q = 0; q < 4; ++q) {
                        float2 v = cpart[w][tt][q * 16 + jl];
                        st += v.x;
                        sp += v.y;
                    }
                atomicAdd(&tot[Jpanel + j], st);
                atomicAdd(&pos[Jpanel + j], sp);
            }
        }
    }

    // ---- R22 completion: barrier drains every wave's vmcnt (atomics complete at the
    //      coherence point), then tid0 releases + counts. NO invalidate anywhere. ----
    __syncthreads();
    if (threadIdx.x == 0)
        slast = (__hip_atomic_fetch_add(cnt, 1u, __ATOMIC_RELEASE, __HIP_MEMORY_SCOPE_AGENT)
                 == TOTAL_BLOCKS - 1) ? 1u : 0u;
    __syncthreads();
    if (slast == 0u) return;

    // ---- Fused finalize (last block only, 256 threads): R18 batched-preload structure ----
    {
        const int tid = threadIdx.x;
        float ls[NUM_CLASSES] = {0.f, 0.f, 0.f, 0.f};
        float lc[NUM_CLASSES] = {0.f, 0.f, 0.f, 0.f};
#pragma unroll 1
        for (int bb = 0; bb < 4; ++bb) {
            float tv[8], pv[8];
            int cl[8];
#pragma unroll
            for (int i = 0; i < 8; ++i) {
                const int n = (bb * 8 + i) * 256 + tid;
                tv[i] = __hip_atomic_load(&tot[n], __ATOMIC_RELAXED, __HIP_MEMORY_SCOPE_AGENT);
                pv[i] = __hip_atomic_load(&pos[n], __ATOMIC_RELAXED, __HIP_MEMORY_SCOPE_AGENT);
                cl[i] = lab[n];
            }
#pragma unroll
            for (int i = 0; i < 8; ++i) {
                float rl = logf(tv[i] + 1e-6f) - logf(pv[i]);
#pragma unroll
                for (int k = 0; k < NUM_CLASSES; ++k) {
                    if (cl[i] == k) {
                        ls[k] += rl;
                        lc[k] += 1.f;
                    }
                }
            }
        }
#pragma unroll
        for (int off = 1; off < 64; off <<= 1) {
#pragma unroll
            for (int k = 0; k < NUM_CLASSES; ++k) {
                ls[k] += __shfl_xor(ls[k], off, 64);
                lc[k] += __shfl_xor(lc[k], off, 64);
            }
        }
        __shared__ float fsum[4][NUM_CLASSES];
        __shared__ float fcnt[4][NUM_CLASSES];
        if ((tid & 63) == 0) {
#pragma unroll
            for (int k = 0; k < NUM_CLASSES; ++k) {
                fsum[wave][k] = ls[k];
                fcnt[wave][k] = lc[k];
            }
        }
        __syncthreads();
        if (tid == 0) {
            float acc = 0.f;
            int present = 0;
            for (int k = 0; k < NUM_CLASSES; ++k) {
                float s = 0.f, c = 0.f;
                for (int w = 0; w < 4; ++w) {
                    s += fsum[w][k];
                    c += fcnt[w][k];
                }
                if (c > 0.f) {
                    acc += s / c;
                    present++;
                }
            }
            out[0] = acc / (float)(present > 0 ? present : 1);
        }
    }
}

extern "C" void kernel_launch(void* const* d_in, const int* in_sizes, int n_in,
                              void* d_out, int out_size, void* d_ws, size_t ws_size,
                              hipStream_t stream) {
    const float* emb = (const float*)d_in[0];  // [2,128,64,64] fp32
    const int* lab = (const int*)d_in[1];      // [2,64,64] int32
    float* out = (float*)d_out;

    unsigned short* ebfT = (unsigned short*)d_ws;            // 2 MiB
    float* pos = (float*)((char*)d_ws + N_PIX * C_DIM * 2);  // [8192] f32
    float* tot = pos + N_PIX;                                // [8192] f32 (contiguous)
    unsigned* cnt = (unsigned*)(tot + N_PIX);                // completion counter

    normscale_kernel<<<N_PIX / 16, 256, 0, stream>>>(emb, ebfT, pos, cnt);

    dim3 grid(64, 33);  // 1..32 off-diag pair cover + 33rd row = diagonal-only blocks
    pairwise_kernel<<<grid, 256, 0, stream>>>(ebfT, lab, pos, tot, cnt, out);
}

// Round 11
// 88.756 us; speedup vs baseline: 1.2424x; 1.2424x over previous
//
#include <hip/hip_runtime.h>
#include <hip/hip_bf16.h>

#define N_PIX 8192
#define C_DIM 128
#define HW 4096
// exp(dot/0.1) = exp2(dot * 14.42695...); fold sqrt of that into each vector.
#define PRESCALE 3.7982825f  // sqrt(log2(e)/0.1)
#define NUM_CLASSES 4

typedef __attribute__((ext_vector_type(8))) short short8;   // 8 x bf16 (4 VGPRs)
typedef __attribute__((ext_vector_type(4))) float float4v;  // 4 x f32 acc

// Fragment-linear layout (R7 win): ebfT[((T*4 + s)*64 + lane)*8 + j] = e[T*16 + lq][s*32 + quad*8 + j],
// lane = quad*16 + lq. Fragment load = base + lane*16B: one coalesced 1KB dwordx4.

// ---------------- Kernel 1: L2-normalize + prescale + bf16 cast into ebfT; zero pos/tot ----------------
__global__ __launch_bounds__(256) void normscale_kernel(const float* __restrict__ emb,
                                                        unsigned short* __restrict__ ebfT,
                                                        float* __restrict__ pz) {
    const int tid = threadIdx.x;
    const int p16 = tid & 15;   // pixel within tile (lq)
    const int g = tid >> 4;     // channel group 0..15 (8 channels each)
    const int n = blockIdx.x * 16 + p16;
    const int b = n >> 12;
    const int hw = n & (HW - 1);
    const float* base = emb + b * (C_DIM * HW) + hw;

    float v[8];
    float ss = 0.f;
#pragma unroll
    for (int i = 0; i < 8; ++i) {
        v[i] = base[(g * 8 + i) * HW];
        ss += v[i] * v[i];
    }
    ss += __shfl_xor(ss, 16, 64);
    ss += __shfl_xor(ss, 32, 64);
    __shared__ float red[4][16];
    const int wv = tid >> 6;
    if ((tid & 63) < 16) red[wv][p16] = ss;
    __syncthreads();
    float tot = red[0][p16] + red[1][p16] + red[2][p16] + red[3][p16];
    float inv = PRESCALE / fmaxf(sqrtf(tot), 1e-12f);

    unsigned short us[8];
#pragma unroll
    for (int i = 0; i < 8; ++i) {
        __hip_bfloat16 h = __float2bfloat16(v[i] * inv);
        us[i] = *reinterpret_cast<unsigned short*>(&h);
    }
    const int s = g >> 2, quad = g & 3;
    unsigned short* dst = ebfT + (((blockIdx.x * 4 + s) * 64 + quad * 16 + p16) << 3);
    *reinterpret_cast<short8*>(dst) = *reinterpret_cast<short8*>(us);

    if (blockIdx.x < 64) pz[blockIdx.x * 256 + tid] = 0.f;
}

// ---------------- Kernel 2: symmetric fused S = e e^T, exp2, row+col sums ----------------
// R23/R24: CLEAN REVERT to the measured optimum (R14/R16/R20 cluster: 87.65-88.37us).
//   (R23 bench was an infra failure — container failed twice; resubmitted unchanged.)
// Grid (64, 33): bi = I-panel (128 rows).
//   d = blockIdx.y+1 in 1..32: off-diag pair blocks, jp=(bi+d)%64; d=1..31 covers each
//   unordered off-diag panel pair once; d=32 double-covers -> bi>=32 culled.
//   d==33: dedicated diagonal blocks (R20 split; neutral but kept - uniform 8-tile blocks).
// LEDGER (10 rounds):
//   WINS: R14 col-side partials -> LDS per tile (ds_write_b64), reduced once per block after
//     ONE __syncthreads, one atomic per column per block (-8us). R18 finalize batched preload
//     (~-5us). Everything else below is locked OUT:
//   R15 FAILED (144): per-block __threadfence = L2 writeback+INVALIDATE on gfx950 (XCD L2s
//     non-coherent) -> poisoned ebfT L2 reuse for all in-flight blocks.
//   R16 NEUTRAL: manual 2-deep register B-pipeline; per-tile load latency already hidden.
//   R17/R18 FAILED (145/109): __launch_bounds__ min-waves>4 ALWAYS spills this kernel
//     (VGPR cap 64/48 -> 130-270MB scratch FETCH/WRITE). (256,4) is FINAL.
//   R20 NEUTRAL: diag straggler split (kept; harmless).
//   R21 FAILED (94.6): atomic-free tail (unique-slot stores + reduce kernel) = +7us; the
//     end-of-kernel relaxed-atomic burst is cheap (<=2us). Atomics exonerated (x2 w/ R13).
//   R22 FAILED (110): per-block __ATOMIC_RELEASE fetch_add = +35us on pairwise. RULE:
//     NO release/acquire-ordered ops per block anywhere in the hot kernel; relaxed atomics
//     only; cross-kernel visibility via kernel boundaries only.
// HARD-WON toolchain rules:
//   *** NEVER fully `#pragma unroll` the MFMA tile loop *** (hoists all B loads -> spill;
//   R6/R10/R11/R12). `#pragma unroll 2` is the sweet spot. R5: no global_load_lds on
//   cache-resident input. R6: no lambdas; reg arrays statically indexed only.
__global__ __launch_bounds__(256, 4) void pairwise_kernel(const unsigned short* __restrict__ ebfT,
                                                          const int* __restrict__ lab,
                                                          float* __restrict__ pos,
                                                          float* __restrict__ tot) {
    const int bi = blockIdx.x;
    const int d = blockIdx.y + 1;          // 1..33
    if (d == 32 && bi >= 32) return;       // wrap double-cover cull (block-uniform)
    const bool diag = (d == 33);           // dedicated diagonal blocks (block-uniform)
    const int jp = diag ? bi : ((bi + d) & 63);
    const int Ipanel = bi << 7;
    const int Jpanel = jp << 7;

    const int wave = threadIdx.x >> 6;
    const int lane = threadIdx.x & 63;
    const int quad = lane >> 4;
    const int lq = lane & 15;

    const int I0 = Ipanel + wave * 32;

    // [wave][tile][lane] col-side partials (x=tot, y=pos). 16 KiB.
    __shared__ float2 cpart[4][8][64];

    // A fragments: tiles (I0>>4), (I0>>4)+1 — coalesced lane*16B loads.
    short8 afrag[2][4];
#pragma unroll
    for (int a = 0; a < 2; ++a) {
        const unsigned short* ab = ebfT + ((((I0 >> 4) + a) * 4) * 64 + lane) * 8;
#pragma unroll
        for (int s = 0; s < 4; ++s)
            afrag[a][s] = *reinterpret_cast<const short8*>(ab + s * 512);
    }
    int lab_row[2][4];
#pragma unroll
    for (int a = 0; a < 2; ++a)
#pragma unroll
        for (int r = 0; r < 4; ++r) lab_row[a][r] = lab[I0 + a * 16 + quad * 4 + r];

    float tacc[2][4] = {};
    float pacc[2][4] = {};

    if (!diag) {
        // ---- Off-diagonal panel pair (no masking, row + col side) ----
        const unsigned short* bbase = ebfT + ((Jpanel >> 4) * 4 * 64 + lane) * 8;
#pragma unroll 2
        for (int t = 0; t < 8; ++t) {
            const int lab_col = lab[Jpanel + t * 16 + lq];
            const unsigned short* bt = bbase + t * 2048;
            short8 bfrag[4];
#pragma unroll
            for (int s = 0; s < 4; ++s)
                bfrag[s] = *reinterpret_cast<const short8*>(bt + s * 512);

            float4v acc0 = {0.f, 0.f, 0.f, 0.f};
            float4v acc1 = {0.f, 0.f, 0.f, 0.f};
#pragma unroll
            for (int s = 0; s < 4; ++s) {
                acc0 = __builtin_amdgcn_mfma_f32_16x16x32_bf16(afrag[0][s], bfrag[s], acc0, 0, 0, 0);
                acc1 = __builtin_amdgcn_mfma_f32_16x16x32_bf16(afrag[1][s], bfrag[s], acc1, 0, 0, 0);
            }

            float colTs = 0.f, colPs = 0.f;
#pragma unroll
            for (int r = 0; r < 4; ++r) {
                float ex = __builtin_amdgcn_exp2f(acc0[r]);
                tacc[0][r] += ex;
                float pxe = (lab_row[0][r] == lab_col) ? ex : 0.f;
                pacc[0][r] += pxe;
                colTs += ex;
                colPs += pxe;
            }
#pragma unroll
            for (int r = 0; r < 4; ++r) {
                float ex = __builtin_amdgcn_exp2f(acc1[r]);
                tacc[1][r] += ex;
                float pxe = (lab_row[1][r] == lab_col) ? ex : 0.f;
                pacc[1][r] += pxe;
                colTs += ex;
                colPs += pxe;
            }
            // fire-and-forget ds_write_b64; reduction deferred to post-barrier gather.
            cpart[wave][t][lane] = make_float2(colTs, colPs);
        }
    } else {
        // ---- Diagonal panel (self-masked, row-side only; col sums == row sums by symmetry) ----
#define EPILOGUE(A, ACC, MASKED)                                            \
    {                                                                       \
        _Pragma("unroll") for (int r = 0; r < 4; ++r) {                     \
            float ex = __builtin_amdgcn_exp2f(ACC[r]);                      \
            if (MASKED) ex = (lq == quad * 4 + r) ? 0.f : ex;               \
            tacc[A][r] += ex;                                               \
            pacc[A][r] += (lab_row[A][r] == lab_col) ? ex : 0.f;            \
        }                                                                   \
    }
        const unsigned short* bbase = ebfT + ((Ipanel >> 4) * 4 * 64 + lane) * 8;
#pragma unroll 2
        for (int t = 0; t < 8; ++t) {
            const int J = Ipanel + t * 16;
            const int lab_col = lab[J + lq];
            const unsigned short* bt = bbase + t * 2048;
            short8 bfrag[4];
#pragma unroll
            for (int s = 0; s < 4; ++s)
                bfrag[s] = *reinterpret_cast<const short8*>(bt + s * 512);

            float4v acc0 = {0.f, 0.f, 0.f, 0.f};
            float4v acc1 = {0.f, 0.f, 0.f, 0.f};
#pragma unroll
            for (int s = 0; s < 4; ++s) {
                acc0 = __builtin_amdgcn_mfma_f32_16x16x32_bf16(afrag[0][s], bfrag[s], acc0, 0, 0, 0);
                acc1 = __builtin_amdgcn_mfma_f32_16x16x32_bf16(afrag[1][s], bfrag[s], acc1, 0, 0, 0);
            }
            if (J == I0) EPILOGUE(0, acc0, true) else EPILOGUE(0, acc0, false);
            if (J == I0 + 16) EPILOGUE(1, acc1, true) else EPILOGUE(1, acc1, false);
        }
#undef EPILOGUE
    }

    // ---- Row-side flush (all blocks): one atomic per row per block ----
    // Register-only + shfl; independent of the barrier, so done BEFORE __syncthreads.
#pragma unroll
    for (int a = 0; a < 2; ++a) {
#pragma unroll
        for (int r = 0; r < 4; ++r) {
            float t = tacc[a][r], p = pacc[a][r];
#pragma unroll
            for (int off = 1; off < 16; off <<= 1) {
                t += __shfl_xor(t, off, 64);
                p += __shfl_xor(p, off, 64);
            }
            if (lq == 0) {
                const int row = I0 + a * 16 + quad * 4 + r;
                atomicAdd(&tot[row], t);
                atomicAdd(&pos[row], p);
            }
        }
    }

    // ---- Col-side gather (off-diag blocks only): one atomic per column ----
    if (!diag) {
        __syncthreads();
        if (threadIdx.x < 128) {
            const int j = threadIdx.x;          // column within J panel
            const int tt = j >> 4, jl = j & 15; // tile, lane-within-tile
            float st = 0.f, sp = 0.f;
#pragma unroll
            for (int w = 0; w < 4; ++w)
#pragma unroll
                for (int q = 0; q < 4; ++q) {
                    float2 v = cpart[w][tt][q * 16 + jl];
                    st += v.x;
                    sp += v.y;
                }
            atomicAdd(&tot[Jpanel + j], st);
            atomicAdd(&pos[Jpanel + j], sp);
        }
    }
}

// ---------------- Kernel 3: row losses + per-class mean of means ----------------
// R18 (kept; measured win): pos/tot come from device-scope atomics (coherence point beyond
//   local L2) -> batch all 24 loads per thread up front so the round-trips overlap into
//   ~one exposed latency; the 16 logf chains run after. Math bit-identical to reference.
__global__ __launch_bounds__(1024) void finalize_kernel(const float* __restrict__ pos,
                                                        const float* __restrict__ tot,
                                                        const int* __restrict__ lab,
                                                        float* __restrict__ out) {
    const int tid = threadIdx.x;
    float tv[8], pv[8];
    int cl[8];
#pragma unroll
    for (int it = 0; it < 8; ++it) {
        const int n = it * 1024 + tid;
        tv[it] = tot[n];
        pv[it] = pos[n];
        cl[it] = lab[n];
    }
    float ls[NUM_CLASSES] = {0.f, 0.f, 0.f, 0.f};
    float lc[NUM_CLASSES] = {0.f, 0.f, 0.f, 0.f};
#pragma unroll
    for (int it = 0; it < 8; ++it) {
        float rl = logf(tv[it] + 1e-6f) - logf(pv[it]);
#pragma unroll
        for (int k = 0; k < NUM_CLASSES; ++k) {
            if (cl[it] == k) {
                ls[k] += rl;
                lc[k] += 1.f;
            }
        }
    }
#pragma unroll
    for (int off = 1; off < 64; off <<= 1) {
#pragma unroll
        for (int k = 0; k < NUM_CLASSES; ++k) {
            ls[k] += __shfl_xor(ls[k], off, 64);
            lc[k] += __shfl_xor(lc[k], off, 64);
        }
    }
    __shared__ float ssum[16][NUM_CLASSES];
    __shared__ float scnt[16][NUM_CLASSES];
    const int wid = tid >> 6;
    if ((tid & 63) == 0) {
#pragma unroll
        for (int k = 0; k < NUM_CLASSES; ++k) {
            ssum[wid][k] = ls[k];
            scnt[wid][k] = lc[k];
        }
    }
    __syncthreads();
    if (tid == 0) {
        float acc = 0.f;
        int present = 0;
        for (int k = 0; k < NUM_CLASSES; ++k) {
            float s = 0.f, c = 0.f;
            for (int w = 0; w < 16; ++w) {
                s += ssum[w][k];
                c += scnt[w][k];
            }
            if (c > 0.f) {
                acc += s / c;
                present++;
            }
        }
        out[0] = acc / (float)(present > 0 ? present : 1);
    }
}

extern "C" void kernel_launch(void* const* d_in, const int* in_sizes, int n_in,
                              void* d_out, int out_size, void* d_ws, size_t ws_size,
                              hipStream_t stream) {
    const float* emb = (const float*)d_in[0];  // [2,128,64,64] fp32
    const int* lab = (const int*)d_in[1];      // [2,64,64] int32
    float* out = (float*)d_out;

    unsigned short* ebfT = (unsigned short*)d_ws;            // 2 MiB
    float* pos = (float*)((char*)d_ws + N_PIX * C_DIM * 2);  // [8192] f32
    float* tot = pos + N_PIX;                                // [8192] f32 (contiguous)

    normscale_kernel<<<N_PIX / 16, 256, 0, stream>>>(emb, ebfT, pos);

    dim3 grid(64, 33);  // 1..32 off-diag pair cover + 33rd row = diagonal-only blocks
    pairwise_kernel<<<grid, 256, 0, stream>>>(ebfT, lab, pos, tot);

    finalize_kernel<<<1, 1024, 0, stream>>>(pos, tot, lab, out);
}

// Round 12
// 87.618 us; speedup vs baseline: 1.2585x; 1.0130x over previous
//
#include <hip/hip_runtime.h>
#include <hip/hip_bf16.h>

#define N_PIX 8192
#define C_DIM 128
#define HW 4096
// exp(dot/0.1) = exp2(dot * 14.42695...); fold sqrt of that into each vector.
#define PRESCALE 3.7982825f  // sqrt(log2(e)/0.1)
#define NUM_CLASSES 4

typedef __attribute__((ext_vector_type(8))) short short8;   // 8 x bf16 (4 VGPRs)
typedef __attribute__((ext_vector_type(4))) float float4v;  // 4 x f32 acc

// Fragment-linear layout (R7 win): ebfT[((T*4 + s)*64 + lane)*8 + j] = e[T*16 + lq][s*32 + quad*8 + j],
// lane = quad*16 + lq. Fragment load = base + lane*16B: one coalesced 1KB dwordx4.

// ---------------- Kernel 1: L2-normalize + prescale + bf16 cast into ebfT; zero pos/tot ----------------
__global__ __launch_bounds__(256) void normscale_kernel(const float* __restrict__ emb,
                                                        unsigned short* __restrict__ ebfT,
                                                        float* __restrict__ pz) {
    const int tid = threadIdx.x;
    const int p16 = tid & 15;   // pixel within tile (lq)
    const int g = tid >> 4;     // channel group 0..15 (8 channels each)
    const int n = blockIdx.x * 16 + p16;
    const int b = n >> 12;
    const int hw = n & (HW - 1);
    const float* base = emb + b * (C_DIM * HW) + hw;

    float v[8];
    float ss = 0.f;
#pragma unroll
    for (int i = 0; i < 8; ++i) {
        v[i] = base[(g * 8 + i) * HW];
        ss += v[i] * v[i];
    }
    ss += __shfl_xor(ss, 16, 64);
    ss += __shfl_xor(ss, 32, 64);
    __shared__ float red[4][16];
    const int wv = tid >> 6;
    if ((tid & 63) < 16) red[wv][p16] = ss;
    __syncthreads();
    float tot = red[0][p16] + red[1][p16] + red[2][p16] + red[3][p16];
    float inv = PRESCALE / fmaxf(sqrtf(tot), 1e-12f);

    unsigned short us[8];
#pragma unroll
    for (int i = 0; i < 8; ++i) {
        __hip_bfloat16 h = __float2bfloat16(v[i] * inv);
        us[i] = *reinterpret_cast<unsigned short*>(&h);
    }
    const int s = g >> 2, quad = g & 3;
    unsigned short* dst = ebfT + (((blockIdx.x * 4 + s) * 64 + quad * 16 + p16) << 3);
    *reinterpret_cast<short8*>(dst) = *reinterpret_cast<short8*>(us);

    if (blockIdx.x < 64) pz[blockIdx.x * 256 + tid] = 0.f;
}

// ---------------- Kernel 2: symmetric fused S = e e^T, exp2, row+col sums ----------------
// R25: UNIFORM ONE-ROUND COVER. The dispatch critical path was doubled in BOTH prior configs:
//   R14: 2016 blocks (<=2048 slots, one round) but d==1 blocks did 16 tiles -> 2x straggler.
//   R20: uniform 8-tile blocks but 2080 working blocks > 2048 co-resident slots -> remainder
//     round. R14 ≈ R20 ≈ 88us because both double the critical path by different means.
//   Now: grid (64,32) = 2048 blocks exactly (one round at 8 blocks/CU) and the 64 diagonal
//   panels are shredded into single 128x16 tiles given to the d=1..8 blocks of each bi
//   (one self-masked diag tile each, row-side only). Max block = 9 tiles vs 8.
//   Coverage: row in panel p gets row-side d=1..31 (+d=32 if p<32) + col-side from blocks
//   (q,d) with (q+d)%64==p -> 63 off-diag panels exactly once; diag panel p = tiles t=0..7
//   from blocks (bi=p, d=t+1). Verified identical sums to R14/R20 cover.
// LEDGER (11 rounds):
//   WINS: R14 col-side partials -> LDS per tile, reduced once per block after ONE
//     __syncthreads, one atomic per column (-8us). R18 finalize batched preload (~-5us).
//   R15 FAILED (144): per-block __threadfence = L2 writeback+INVALIDATE on gfx950 (XCD L2s
//     non-coherent) -> poisoned ebfT L2 reuse. NO fences ever.
//   R16 NEUTRAL: manual 2-deep register B-pipeline; load latency already hidden.
//   R17/R18 FAILED (145/109): __launch_bounds__ min-waves>4 ALWAYS spills (VGPR cap 64/48
//     -> 130-270MB scratch). (256,4) is FINAL.
//   R21 FAILED (94.6): unique-slot stores + reduce kernel = +7us; relaxed-atomic tail is
//     cheap. R22 FAILED (110): per-block __ATOMIC_RELEASE fetch_add = +35us. RULE: relaxed
//     atomics only; cross-kernel visibility via kernel boundaries only.
// HARD-WON toolchain rules:
//   *** NEVER fully `#pragma unroll` the MFMA tile loop *** (hoists all B loads -> spill;
//   R6/R10/R11/R12). `#pragma unroll 2` is the sweet spot. R5: no global_load_lds on
//   cache-resident input. R6: no lambdas; reg arrays statically indexed only.
__global__ __launch_bounds__(256, 4) void pairwise_kernel(const unsigned short* __restrict__ ebfT,
                                                          const int* __restrict__ lab,
                                                          float* __restrict__ pos,
                                                          float* __restrict__ tot) {
    const int bi = blockIdx.x;
    const int d = blockIdx.y + 1;          // 1..32
    if (d == 32 && bi >= 32) return;       // wrap double-cover cull (block-uniform)
    const int jp = (bi + d) & 63;
    const int Ipanel = bi << 7;
    const int Jpanel = jp << 7;

    const int wave = threadIdx.x >> 6;
    const int lane = threadIdx.x & 63;
    const int quad = lane >> 4;
    const int lq = lane & 15;

    const int I0 = Ipanel + wave * 32;

    // [wave][tile][lane] col-side partials (x=tot, y=pos). 16 KiB.
    __shared__ float2 cpart[4][8][64];

    // A fragments: tiles (I0>>4), (I0>>4)+1 — coalesced lane*16B loads.
    short8 afrag[2][4];
#pragma unroll
    for (int a = 0; a < 2; ++a) {
        const unsigned short* ab = ebfT + ((((I0 >> 4) + a) * 4) * 64 + lane) * 8;
#pragma unroll
        for (int s = 0; s < 4; ++s)
            afrag[a][s] = *reinterpret_cast<const short8*>(ab + s * 512);
    }
    int lab_row[2][4];
#pragma unroll
    for (int a = 0; a < 2; ++a)
#pragma unroll
        for (int r = 0; r < 4; ++r) lab_row[a][r] = lab[I0 + a * 16 + quad * 4 + r];

    float tacc[2][4] = {};
    float pacc[2][4] = {};

    // ---- Off-diagonal panel pair (no masking, row + col side), 8 tiles ----
    {
        const unsigned short* bbase = ebfT + ((Jpanel >> 4) * 4 * 64 + lane) * 8;
#pragma unroll 2
        for (int t = 0; t < 8; ++t) {
            const int lab_col = lab[Jpanel + t * 16 + lq];
            const unsigned short* bt = bbase + t * 2048;
            short8 bfrag[4];
#pragma unroll
            for (int s = 0; s < 4; ++s)
                bfrag[s] = *reinterpret_cast<const short8*>(bt + s * 512);

            float4v acc0 = {0.f, 0.f, 0.f, 0.f};
            float4v acc1 = {0.f, 0.f, 0.f, 0.f};
#pragma unroll
            for (int s = 0; s < 4; ++s) {
                acc0 = __builtin_amdgcn_mfma_f32_16x16x32_bf16(afrag[0][s], bfrag[s], acc0, 0, 0, 0);
                acc1 = __builtin_amdgcn_mfma_f32_16x16x32_bf16(afrag[1][s], bfrag[s], acc1, 0, 0, 0);
            }

            float colTs = 0.f, colPs = 0.f;
#pragma unroll
            for (int r = 0; r < 4; ++r) {
                float ex = __builtin_amdgcn_exp2f(acc0[r]);
                tacc[0][r] += ex;
                float pxe = (lab_row[0][r] == lab_col) ? ex : 0.f;
                pacc[0][r] += pxe;
                colTs += ex;
                colPs += pxe;
            }
#pragma unroll
            for (int r = 0; r < 4; ++r) {
                float ex = __builtin_amdgcn_exp2f(acc1[r]);
                tacc[1][r] += ex;
                float pxe = (lab_row[1][r] == lab_col) ? ex : 0.f;
                pacc[1][r] += pxe;
                colTs += ex;
                colPs += pxe;
            }
            // fire-and-forget ds_write_b64; reduction deferred to post-barrier gather.
            cpart[wave][t][lane] = make_float2(colTs, colPs);
        }
    }

    // ---- R25: one diagonal tile (t = d-1) of panel bi for d<=8 blocks; self-masked,
    //      row-side only (diag panel's col sums == row sums by symmetry; whole panel is
    //      covered row-side across the 8 blocks d=1..8 of this bi). ----
#define EPILOGUE(A, ACC, MASKED)                                            \
    {                                                                       \
        _Pragma("unroll") for (int r = 0; r < 4; ++r) {                     \
            float ex = __builtin_amdgcn_exp2f(ACC[r]);                      \
            if (MASKED) ex = (lq == quad * 4 + r) ? 0.f : ex;               \
            tacc[A][r] += ex;                                               \
            pacc[A][r] += (lab_row[A][r] == lab_col) ? ex : 0.f;            \
        }                                                                   \
    }
    if (d <= 8) {
        const int t = d - 1;
        const int J = Ipanel + t * 16;
        const int lab_col = lab[J + lq];
        const unsigned short* bt = ebfT + ((Ipanel >> 4) * 4 * 64 + lane) * 8 + t * 2048;
        short8 bfrag[4];
#pragma unroll
        for (int s = 0; s < 4; ++s)
            bfrag[s] = *reinterpret_cast<const short8*>(bt + s * 512);

        float4v acc0 = {0.f, 0.f, 0.f, 0.f};
        float4v acc1 = {0.f, 0.f, 0.f, 0.f};
#pragma unroll
        for (int s = 0; s < 4; ++s) {
            acc0 = __builtin_amdgcn_mfma_f32_16x16x32_bf16(afrag[0][s], bfrag[s], acc0, 0, 0, 0);
            acc1 = __builtin_amdgcn_mfma_f32_16x16x32_bf16(afrag[1][s], bfrag[s], acc1, 0, 0, 0);
        }
        if (J == I0) EPILOGUE(0, acc0, true) else EPILOGUE(0, acc0, false);
        if (J == I0 + 16) EPILOGUE(1, acc1, true) else EPILOGUE(1, acc1, false);
    }
#undef EPILOGUE

    // ---- Row-side flush (covers off-diag + diag tile): one atomic per row per block ----
    // Register-only + shfl; independent of the barrier, so done BEFORE __syncthreads.
#pragma unroll
    for (int a = 0; a < 2; ++a) {
#pragma unroll
        for (int r = 0; r < 4; ++r) {
            float t = tacc[a][r], p = pacc[a][r];
#pragma unroll
            for (int off = 1; off < 16; off <<= 1) {
                t += __shfl_xor(t, off, 64);
                p += __shfl_xor(p, off, 64);
            }
            if (lq == 0) {
                const int row = I0 + a * 16 + quad * 4 + r;
                atomicAdd(&tot[row], t);
                atomicAdd(&pos[row], p);
            }
        }
    }

    // ---- Col-side gather: sum 4 waves x 4 quads per column, one atomic per column ----
    __syncthreads();
    if (threadIdx.x < 128) {
        const int j = threadIdx.x;          // column within J panel
        const int tt = j >> 4, jl = j & 15; // tile, lane-within-tile
        float st = 0.f, sp = 0.f;
#pragma unroll
        for (int w = 0; w < 4; ++w)
#pragma unroll
            for (int q = 0; q < 4; ++q) {
                float2 v = cpart[w][tt][q * 16 + jl];
                st += v.x;
                sp += v.y;
            }
        atomicAdd(&tot[Jpanel + j], st);
        atomicAdd(&pos[Jpanel + j], sp);
    }
}

// ---------------- Kernel 3: row losses + per-class mean of means ----------------
// R18 (kept; measured win): pos/tot come from device-scope atomics (coherence point beyond
//   local L2) -> batch all 24 loads per thread up front so the round-trips overlap into
//   ~one exposed latency; the 16 logf chains run after. Math bit-identical to reference.
__global__ __launch_bounds__(1024) void finalize_kernel(const float* __restrict__ pos,
                                                        const float* __restrict__ tot,
                                                        const int* __restrict__ lab,
                                                        float* __restrict__ out) {
    const int tid = threadIdx.x;
    float tv[8], pv[8];
    int cl[8];
#pragma unroll
    for (int it = 0; it < 8; ++it) {
        const int n = it * 1024 + tid;
        tv[it] = tot[n];
        pv[it] = pos[n];
        cl[it] = lab[n];
    }
    float ls[NUM_CLASSES] = {0.f, 0.f, 0.f, 0.f};
    float lc[NUM_CLASSES] = {0.f, 0.f, 0.f, 0.f};
#pragma unroll
    for (int it = 0; it < 8; ++it) {
        float rl = logf(tv[it] + 1e-6f) - logf(pv[it]);
#pragma unroll
        for (int k = 0; k < NUM_CLASSES; ++k) {
            if (cl[it] == k) {
                ls[k] += rl;
                lc[k] += 1.f;
            }
        }
    }
#pragma unroll
    for (int off = 1; off < 64; off <<= 1) {
#pragma unroll
        for (int k = 0; k < NUM_CLASSES; ++k) {
            ls[k] += __shfl_xor(ls[k], off, 64);
            lc[k] += __shfl_xor(lc[k], off, 64);
        }
    }
    __shared__ float ssum[16][NUM_CLASSES];
    __shared__ float scnt[16][NUM_CLASSES];
    const int wid = tid >> 6;
    if ((tid & 63) == 0) {
#pragma unroll
        for (int k = 0; k < NUM_CLASSES; ++k) {
            ssum[wid][k] = ls[k];
            scnt[wid][k] = lc[k];
        }
    }
    __syncthreads();
    if (tid == 0) {
        float acc = 0.f;
        int present = 0;
        for (int k = 0; k < NUM_CLASSES; ++k) {
            float s = 0.f, c = 0.f;
            for (int w = 0; w < 16; ++w) {
                s += ssum[w][k];
                c += scnt[w][k];
            }
            if (c > 0.f) {
                acc += s / c;
                present++;
            }
        }
        out[0] = acc / (float)(present > 0 ? present : 1);
    }
}

extern "C" void kernel_launch(void* const* d_in, const int* in_sizes, int n_in,
                              void* d_out, int out_size, void* d_ws, size_t ws_size,
                              hipStream_t stream) {
    const float* emb = (const float*)d_in[0];  // [2,128,64,64] fp32
    const int* lab = (const int*)d_in[1];      // [2,64,64] int32
    float* out = (float*)d_out;

    unsigned short* ebfT = (unsigned short*)d_ws;            // 2 MiB
    float* pos = (float*)((char*)d_ws + N_PIX * C_DIM * 2);  // [8192] f32
    float* tot = pos + N_PIX;                                // [8192] f32 (contiguous)

    normscale_kernel<<<N_PIX / 16, 256, 0, stream>>>(emb, ebfT, pos);

    dim3 grid(64, 32);  // one-round uniform cover; diag tiles folded into d=1..8 blocks
    pairwise_kernel<<<grid, 256, 0, stream>>>(ebfT, lab, pos, tot);

    finalize_kernel<<<1, 1024, 0, stream>>>(pos, tot, lab, out);
}

// Round 13
// 86.547 us; speedup vs baseline: 1.2741x; 1.0124x over previous
//
#include <hip/hip_runtime.h>
#include <hip/hip_bf16.h>

#define N_PIX 8192
#define C_DIM 128
#define HW 4096
// exp(dot/0.1) = exp2(dot * 14.42695...); fold sqrt of that into each vector.
#define PRESCALE 3.7982825f  // sqrt(log2(e)/0.1)
#define NUM_CLASSES 4

typedef __attribute__((ext_vector_type(8))) short short8;   // 8 x bf16 (4 VGPRs)
typedef __attribute__((ext_vector_type(4))) float float4v;  // 4 x f32 acc

// Fragment-linear layout (R7 win): ebfT[((T*4 + s)*64 + lane)*8 + j] = e[T*16 + lq][s*32 + quad*8 + j],
// lane = quad*16 + lq. Fragment load = base + lane*16B: one coalesced 1KB dwordx4.
// Tile T is a CONTIGUOUS 4KB block: bytes [T*4096, (T+1)*4096).

// ---------------- Kernel 1: L2-normalize + prescale + bf16 cast into ebfT; zero pos/tot ----------------
__global__ __launch_bounds__(256) void normscale_kernel(const float* __restrict__ emb,
                                                        unsigned short* __restrict__ ebfT,
                                                        float* __restrict__ pz) {
    const int tid = threadIdx.x;
    const int p16 = tid & 15;   // pixel within tile (lq)
    const int g = tid >> 4;     // channel group 0..15 (8 channels each)
    const int n = blockIdx.x * 16 + p16;
    const int b = n >> 12;
    const int hw = n & (HW - 1);
    const float* base = emb + b * (C_DIM * HW) + hw;

    float v[8];
    float ss = 0.f;
#pragma unroll
    for (int i = 0; i < 8; ++i) {
        v[i] = base[(g * 8 + i) * HW];
        ss += v[i] * v[i];
    }
    ss += __shfl_xor(ss, 16, 64);
    ss += __shfl_xor(ss, 32, 64);
    __shared__ float red[4][16];
    const int wv = tid >> 6;
    if ((tid & 63) < 16) red[wv][p16] = ss;
    __syncthreads();
    float tot = red[0][p16] + red[1][p16] + red[2][p16] + red[3][p16];
    float inv = PRESCALE / fmaxf(sqrtf(tot), 1e-12f);

    unsigned short us[8];
#pragma unroll
    for (int i = 0; i < 8; ++i) {
        __hip_bfloat16 h = __float2bfloat16(v[i] * inv);
        us[i] = *reinterpret_cast<unsigned short*>(&h);
    }
    const int s = g >> 2, quad = g & 3;
    unsigned short* dst = ebfT + (((blockIdx.x * 4 + s) * 64 + quad * 16 + p16) << 3);
    *reinterpret_cast<short8*>(dst) = *reinterpret_cast<short8*>(us);

    if (blockIdx.x < 64) pz[blockIdx.x * 256 + tid] = 0.f;
}

// ---------------- Kernel 2: symmetric fused S = e e^T, exp2, row+col sums ----------------
// R26: LDS-STAGED B TILES. All 4 waves per block previously loaded byte-identical B
//   fragments from L2 -> 4x redundant read traffic (~277MB total, ~35MB/XCD ≈ 8us+ serial
//   L2 floor; 32KB panel also exactly thrashes the 32KB L1). Now 256 threads cooperatively
//   load each 4KB B-tile ONCE (one dwordx4 each, issued one tile ahead), ds_write into a
//   double-buffered LDS stage, ONE __syncthreads per tile; waves read fragments from LDS.
//   B L2 traffic /4. This is plain reg->ds_write staging - NOT the banned global_load_lds
//   (R5's failure was the async direct-to-LDS instruction on cache-resident input).
//   NB: R16 pipelining null showed load LATENCY is hidden; staging attacks BANDWIDTH,
//   which pipelining cannot.
// R25: uniform one-round cover (diag shredded into d=1..8 blocks as 1 extra tile). Kept.
//   Scheduling-shape theories falsified 3 ways (R14 2x-straggler = R20 remainder-round =
//   R25 uniform ≈ 88us): dispatch critical path is NOT the limiter.
// LEDGER (12 rounds):
//   WINS: R14 col partials->LDS, one atomic/col/block (-8us). R18 finalize batched preload
//     (~-5us). LOCKED OUT: R15 __threadfence (L2 wb+INVALIDATE, 144us). R17/R18
//     launch_bounds min-waves>4 (ALWAYS spills: unified VGPR+AGPR ~120/wave; (256,4) FINAL;
//     natural occupancy 4 blocks/CU). R21 partials+reduce kernel (+7us; relaxed-atomic tail
//     is cheap). R22 per-block __ATOMIC_RELEASE (+35us; relaxed atomics ONLY, cross-kernel
//     visibility via kernel boundaries only).
// HARD-WON toolchain rules:
//   *** NEVER fully `#pragma unroll` the MFMA tile loop *** (hoists all B loads -> spill;
//   R6/R10/R11/R12). Staged loop uses `#pragma unroll 1` (explicit 2-deep pipeline).
//   R6: no lambdas; reg arrays statically indexed only (LDS arrays may be runtime-indexed).
__global__ __launch_bounds__(256, 4) void pairwise_kernel(const unsigned short* __restrict__ ebfT,
                                                          const int* __restrict__ lab,
                                                          float* __restrict__ pos,
                                                          float* __restrict__ tot) {
    const int bi = blockIdx.x;
    const int d = blockIdx.y + 1;          // 1..32
    if (d == 32 && bi >= 32) return;       // wrap double-cover cull (block-uniform)
    const int jp = (bi + d) & 63;
    const int Ipanel = bi << 7;
    const int Jpanel = jp << 7;

    const int tid = threadIdx.x;
    const int wave = tid >> 6;
    const int lane = tid & 63;
    const int quad = lane >> 4;
    const int lq = lane & 15;

    const int I0 = Ipanel + wave * 32;

    // [wave][tile][lane] col-side partials (x=tot, y=pos). 16 KiB.
    __shared__ float2 cpart[4][8][64];
    // Double-buffered 4KB B tile. 8 KiB.
    __shared__ short8 bstage[2][256];

    // A fragments: tiles (I0>>4), (I0>>4)+1 — coalesced lane*16B loads.
    short8 afrag[2][4];
#pragma unroll
    for (int a = 0; a < 2; ++a) {
        const unsigned short* ab = ebfT + ((((I0 >> 4) + a) * 4) * 64 + lane) * 8;
#pragma unroll
        for (int s = 0; s < 4; ++s)
            afrag[a][s] = *reinterpret_cast<const short8*>(ab + s * 512);
    }
    int lab_row[2][4];
#pragma unroll
    for (int a = 0; a < 2; ++a)
#pragma unroll
        for (int r = 0; r < 4; ++r) lab_row[a][r] = lab[I0 + a * 16 + quad * 4 + r];

    float tacc[2][4] = {};
    float pacc[2][4] = {};

    // ---- Off-diagonal panel pair (no masking, row + col side), 8 LDS-staged tiles ----
    {
        const unsigned short* bpan = ebfT + (jp * 8) * 2048;  // panel = 8 contiguous 4KB tiles
        short8 stg = *reinterpret_cast<const short8*>(bpan + tid * 8);  // tile 0
        bstage[0][tid] = stg;
        __syncthreads();
#pragma unroll 1
        for (int t = 0; t < 8; ++t) {
            // issue next tile's global load early (latency hides under compute)
            if (t < 7)
                stg = *reinterpret_cast<const short8*>(bpan + (t + 1) * 2048 + tid * 8);
            const int lab_col = lab[Jpanel + t * 16 + lq];

            short8 bfrag[4];
#pragma unroll
            for (int s = 0; s < 4; ++s)
                bfrag[s] = bstage[t & 1][s * 64 + lane];

            float4v acc0 = {0.f, 0.f, 0.f, 0.f};
            float4v acc1 = {0.f, 0.f, 0.f, 0.f};
#pragma unroll
            for (int s = 0; s < 4; ++s) {
                acc0 = __builtin_amdgcn_mfma_f32_16x16x32_bf16(afrag[0][s], bfrag[s], acc0, 0, 0, 0);
                acc1 = __builtin_amdgcn_mfma_f32_16x16x32_bf16(afrag[1][s], bfrag[s], acc1, 0, 0, 0);
            }

            float colTs = 0.f, colPs = 0.f;
#pragma unroll
            for (int r = 0; r < 4; ++r) {
                float ex = __builtin_amdgcn_exp2f(acc0[r]);
                tacc[0][r] += ex;
                float pxe = (lab_row[0][r] == lab_col) ? ex : 0.f;
                pacc[0][r] += pxe;
                colTs += ex;
                colPs += pxe;
            }
#pragma unroll
            for (int r = 0; r < 4; ++r) {
                float ex = __builtin_amdgcn_exp2f(acc1[r]);
                tacc[1][r] += ex;
                float pxe = (lab_row[1][r] == lab_col) ? ex : 0.f;
                pacc[1][r] += pxe;
                colTs += ex;
                colPs += pxe;
            }
            // fire-and-forget ds_write_b64; reduction deferred to post-barrier gather.
            cpart[wave][t][lane] = make_float2(colTs, colPs);

            // write next tile into the other buffer; barrier publishes it (and guards
            // buffer (t+1)&1 against the reads that finished at the previous barrier).
            if (t < 7)
                bstage[(t + 1) & 1][tid] = stg;
            __syncthreads();
        }
    }

    // ---- R25: one diagonal tile (t = d-1) of panel bi for d<=8 blocks; self-masked,
    //      row-side only (direct L2 loads; only 512 such tiles total). ----
#define EPILOGUE(A, ACC, MASKED)                                            \
    {                                                                       \
        _Pragma("unroll") for (int r = 0; r < 4; ++r) {                     \
            float ex = __builtin_amdgcn_exp2f(ACC[r]);                      \
            if (MASKED) ex = (lq == quad * 4 + r) ? 0.f : ex;               \
            tacc[A][r] += ex;                                               \
            pacc[A][r] += (lab_row[A][r] == lab_col) ? ex : 0.f;            \
        }                                                                   \
    }
    if (d <= 8) {
        const int t = d - 1;
        const int J = Ipanel + t * 16;
        const int lab_col = lab[J + lq];
        const unsigned short* bt = ebfT + ((Ipanel >> 4) * 4 * 64 + lane) * 8 + t * 2048;
        short8 bfrag[4];
#pragma unroll
        for (int s = 0; s < 4; ++s)
            bfrag[s] = *reinterpret_cast<const short8*>(bt + s * 512);

        float4v acc0 = {0.f, 0.f, 0.f, 0.f};
        float4v acc1 = {0.f, 0.f, 0.f, 0.f};
#pragma unroll
        for (int s = 0; s < 4; ++s) {
            acc0 = __builtin_amdgcn_mfma_f32_16x16x32_bf16(afrag[0][s], bfrag[s], acc0, 0, 0, 0);
            acc1 = __builtin_amdgcn_mfma_f32_16x16x32_bf16(afrag[1][s], bfrag[s], acc1, 0, 0, 0);
        }
        if (J == I0) EPILOGUE(0, acc0, true) else EPILOGUE(0, acc0, false);
        if (J == I0 + 16) EPILOGUE(1, acc1, true) else EPILOGUE(1, acc1, false);
    }
#undef EPILOGUE

    // ---- Row-side flush (covers off-diag + diag tile): one atomic per row per block ----
    // Register-only + shfl; independent of the barrier, so done BEFORE __syncthreads.
#pragma unroll
    for (int a = 0; a < 2; ++a) {
#pragma unroll
        for (int r = 0; r < 4; ++r) {
            float t = tacc[a][r], p = pacc[a][r];
#pragma unroll
            for (int off = 1; off < 16; off <<= 1) {
                t += __shfl_xor(t, off, 64);
                p += __shfl_xor(p, off, 64);
            }
            if (lq == 0) {
                const int row = I0 + a * 16 + quad * 4 + r;
                atomicAdd(&tot[row], t);
                atomicAdd(&pos[row], p);
            }
        }
    }

    // ---- Col-side gather: sum 4 waves x 4 quads per column, one atomic per column ----
    __syncthreads();
    if (threadIdx.x < 128) {
        const int j = threadIdx.x;          // column within J panel
        const int tt = j >> 4, jl = j & 15; // tile, lane-within-tile
        float st = 0.f, sp = 0.f;
#pragma unroll
        for (int w = 0; w < 4; ++w)
#pragma unroll
            for (int q = 0; q < 4; ++q) {
                float2 v = cpart[w][tt][q * 16 + jl];
                st += v.x;
                sp += v.y;
            }
        atomicAdd(&tot[Jpanel + j], st);
        atomicAdd(&pos[Jpanel + j], sp);
    }
}

// ---------------- Kernel 3: row losses + per-class mean of means ----------------
// R18 (kept; measured win): pos/tot come from device-scope atomics (coherence point beyond
//   local L2) -> batch all 24 loads per thread up front so the round-trips overlap into
//   ~one exposed latency; the 16 logf chains run after. Math bit-identical to reference.
__global__ __launch_bounds__(1024) void finalize_kernel(const float* __restrict__ pos,
                                                        const float* __restrict__ tot,
                                                        const int* __restrict__ lab,
                                                        float* __restrict__ out) {
    const int tid = threadIdx.x;
    float tv[8], pv[8];
    int cl[8];
#pragma unroll
    for (int it = 0; it < 8; ++it) {
        const int n = it * 1024 + tid;
        tv[it] = tot[n];
        pv[it] = pos[n];
        cl[it] = lab[n];
    }
    float ls[NUM_CLASSES] = {0.f, 0.f, 0.f, 0.f};
    float lc[NUM_CLASSES] = {0.f, 0.f, 0.f, 0.f};
#pragma unroll
    for (int it = 0; it < 8; ++it) {
        float rl = logf(tv[it] + 1e-6f) - logf(pv[it]);
#pragma unroll
        for (int k = 0; k < NUM_CLASSES; ++k) {
            if (cl[it] == k) {
                ls[k] += rl;
                lc[k] += 1.f;
            }
        }
    }
#pragma unroll
    for (int off = 1; off < 64; off <<= 1) {
#pragma unroll
        for (int k = 0; k < NUM_CLASSES; ++k) {
            ls[k] += __shfl_xor(ls[k], off, 64);
            lc[k] += __shfl_xor(lc[k], off, 64);
        }
    }
    __shared__ float ssum[16][NUM_CLASSES];
    __shared__ float scnt[16][NUM_CLASSES];
    const int wid = tid >> 6;
    if ((tid & 63) == 0) {
#pragma unroll
        for (int k = 0; k < NUM_CLASSES; ++k) {
            ssum[wid][k] = ls[k];
            scnt[wid][k] = lc[k];
        }
    }
    __syncthreads();
    if (tid == 0) {
        float acc = 0.f;
        int present = 0;
        for (int k = 0; k < NUM_CLASSES; ++k) {
            float s = 0.f, c = 0.f;
            for (int w = 0; w < 16; ++w) {
                s += ssum[w][k];
                c += scnt[w][k];
            }
            if (c > 0.f) {
                acc += s / c;
                present++;
            }
        }
        out[0] = acc / (float)(present > 0 ? present : 1);
    }
}

extern "C" void kernel_launch(void* const* d_in, const int* in_sizes, int n_in,
                              void* d_out, int out_size, void* d_ws, size_t ws_size,
                              hipStream_t stream) {
    const float* emb = (const float*)d_in[0];  // [2,128,64,64] fp32
    const int* lab = (const int*)d_in[1];      // [2,64,64] int32
    float* out = (float*)d_out;

    unsigned short* ebfT = (unsigned short*)d_ws;            // 2 MiB
    float* pos = (float*)((char*)d_ws + N_PIX * C_DIM * 2);  // [8192] f32
    float* tot = pos + N_PIX;                                // [8192] f32 (contiguous)

    normscale_kernel<<<N_PIX / 16, 256, 0, stream>>>(emb, ebfT, pos);

    dim3 grid(64, 32);  // one-round uniform cover; diag tiles folded into d=1..8 blocks
    pairwise_kernel<<<grid, 256, 0, stream>>>(ebfT, lab, pos, tot);

    finalize_kernel<<<1, 1024, 0, stream>>>(pos, tot, lab, out);
}